// Round 1
// baseline (171.592 us; speedup 1.0000x reference)
//
#include <hip/hip_runtime.h>

typedef float    f32x4  __attribute__((ext_vector_type(4)));
typedef __bf16   bf16x8 __attribute__((ext_vector_type(8)));
typedef unsigned short u16;
typedef unsigned short u16x8 __attribute__((ext_vector_type(8)));
typedef int      i32x4  __attribute__((ext_vector_type(4)));

#define NN   8192
#define FIN  512
#define FOUT 64
#define LOG2E 1.4426950408889634f

#if __has_builtin(__builtin_amdgcn_exp2f)
#define EXP2F(x) __builtin_amdgcn_exp2f(x)
#else
#define EXP2F(x) exp2f(x)
#endif

__device__ __forceinline__ u16 f2bf(float f) {          // f32 -> bf16 RNE
    unsigned int u = __float_as_uint(f);
    u += 0x7FFFu + ((u >> 16) & 1u);
    return (u16)(u >> 16);
}
__device__ __forceinline__ float bf2f(u16 b) {
    return __uint_as_float(((unsigned int)b) << 16);
}

// ---------------------------------------------------------------------------
// K0: W (512x64 f32) -> WT_hi/WT_lo (64x512 bf16, transposed hi/lo split)
// ---------------------------------------------------------------------------
__global__ __launch_bounds__(256) void k_wt(const float* __restrict__ W,
                                            u16* __restrict__ wt_hi,
                                            u16* __restrict__ wt_lo) {
    int t = blockIdx.x * 256 + threadIdx.x;   // 0..32767
    int k = t >> 6, c = t & 63;
    float w = W[t];                            // W[k*64+c]
    u16 h = f2bf(w);
    wt_hi[c * FIN + k] = h;
    wt_lo[c * FIN + k] = f2bf(w - bf2f(h));
}

// ---------------------------------------------------------------------------
// K1: z = input @ W  (3-term bf16 MFMA split ~ f32 exact), plus
//     s1p = (z@a1)*log2e, s2p = (z@a2)*log2e  from the f32 accumulators.
//     grid 256 x 128thr(2 waves), wave = one 16-row m-tile.
// ---------------------------------------------------------------------------
__global__ __launch_bounds__(128) void k_zgemm(
        const float* __restrict__ in, const u16* __restrict__ wt_hi,
        const u16* __restrict__ wt_lo, const float* __restrict__ a,
        float* __restrict__ z, float* __restrict__ s1p, float* __restrict__ s2p)
{
    const int wv = threadIdx.x >> 6;
    const int l  = threadIdx.x & 63;
    const int lr = l & 15, lk = l >> 4;
    const int mtile = blockIdx.x * 2 + wv;        // 0..511
    const int row_base = mtile * 16;

    f32x4 acc[4] = {};
    const float* inrow = in + (size_t)(row_base + lr) * FIN;

    for (int ks = 0; ks < 16; ++ks) {
        const int k0 = ks * 32 + lk * 8;
        const f32x4 v0 = *(const f32x4*)(inrow + k0);
        const f32x4 v1 = *(const f32x4*)(inrow + k0 + 4);
        u16x8 hv, lv;
#pragma unroll
        for (int i = 0; i < 4; ++i) {
            u16 h = f2bf(v0[i]); hv[i] = h; lv[i] = f2bf(v0[i] - bf2f(h));
        }
#pragma unroll
        for (int i = 0; i < 4; ++i) {
            u16 h = f2bf(v1[i]); hv[4 + i] = h; lv[4 + i] = f2bf(v1[i] - bf2f(h));
        }
        const bf16x8 ahi = __builtin_bit_cast(bf16x8, hv);
        const bf16x8 alo = __builtin_bit_cast(bf16x8, lv);
#pragma unroll
        for (int nt = 0; nt < 4; ++nt) {
            const int wrow = nt * 16 + lr;
            const bf16x8 bh = __builtin_bit_cast(bf16x8, *(const u16x8*)(wt_hi + (size_t)wrow * FIN + k0));
            const bf16x8 bl = __builtin_bit_cast(bf16x8, *(const u16x8*)(wt_lo + (size_t)wrow * FIN + k0));
            acc[nt] = __builtin_amdgcn_mfma_f32_16x16x32_bf16(ahi, bh, acc[nt], 0, 0, 0);
            acc[nt] = __builtin_amdgcn_mfma_f32_16x16x32_bf16(alo, bh, acc[nt], 0, 0, 0);
            acc[nt] = __builtin_amdgcn_mfma_f32_16x16x32_bf16(ahi, bl, acc[nt], 0, 0, 0);
        }
    }

    // store z (f32)
#pragma unroll
    for (int nt = 0; nt < 4; ++nt)
#pragma unroll
        for (int r = 0; r < 4; ++r)
            z[(size_t)(row_base + lk * 4 + r) * FOUT + nt * 16 + lr] = acc[nt][r];

    // s1/s2 from exact accumulators
    float a1c[4], a2c[4];
#pragma unroll
    for (int nt = 0; nt < 4; ++nt) {
        a1c[nt] = a[nt * 16 + lr];
        a2c[nt] = a[64 + nt * 16 + lr];
    }
#pragma unroll
    for (int r = 0; r < 4; ++r) {
        float s1 = 0.f, s2 = 0.f;
#pragma unroll
        for (int nt = 0; nt < 4; ++nt) {
            s1 += acc[nt][r] * a1c[nt];
            s2 += acc[nt][r] * a2c[nt];
        }
#pragma unroll
        for (int m = 1; m <= 8; m <<= 1) {
            s1 += __shfl_xor(s1, m, 64);
            s2 += __shfl_xor(s2, m, 64);
        }
        if (lr == 0) {
            s1p[row_base + lk * 4 + r] = s1 * LOG2E;
            s2p[row_base + lk * 4 + r] = s2 * LOG2E;
        }
    }
}

// ---------------------------------------------------------------------------
// K2: zT_hi/zT_lo (64 x 8192 bf16) from z (8192x64 f32). grid 256 x 128.
// ---------------------------------------------------------------------------
__global__ __launch_bounds__(128) void k_zt(const float* __restrict__ z,
                                            u16* __restrict__ zt_hi,
                                            u16* __restrict__ zt_lo) {
    const int t = threadIdx.x;
    const int c = t & 63, jq = t >> 6;            // jq 0..1
    const int j0 = blockIdx.x * 32 + jq * 16;
    u16x8 h0{}, h1{}, l0{}, l1{};
#pragma unroll
    for (int i = 0; i < 8; ++i) {
        float v = z[(size_t)(j0 + i) * FOUT + c];
        u16 h = f2bf(v); h0[i] = h; l0[i] = f2bf(v - bf2f(h));
    }
#pragma unroll
    for (int i = 0; i < 8; ++i) {
        float v = z[(size_t)(j0 + 8 + i) * FOUT + c];
        u16 h = f2bf(v); h1[i] = h; l1[i] = f2bf(v - bf2f(h));
    }
    *(u16x8*)(zt_hi + (size_t)c * NN + j0)     = h0;
    *(u16x8*)(zt_hi + (size_t)c * NN + j0 + 8) = h1;
    *(u16x8*)(zt_lo + (size_t)c * NN + j0)     = l0;
    *(u16x8*)(zt_lo + (size_t)c * NN + j0 + 8) = l1;
}

// ---------------------------------------------------------------------------
// K3: fused masked-softmax attention + PV.
// 256 blocks x 512 thr (8 waves). Block = 32 rows, iterates j in 256-tiles.
// Wave wv: nh = wv&1 (32-col half), kq = wv>>1 (k-quarter of the tile).
// Phase A computes w in exact MFMA A-fragment layout -> LDS (double buffer,
// ONE barrier per tile). adj prefetched 1 tile ahead, issued post-barrier.
// ---------------------------------------------------------------------------
__global__ __launch_bounds__(512, 1) void k_attn(
        const int* __restrict__ adj, const u16* __restrict__ zt_hi,
        const u16* __restrict__ zt_lo, const float* __restrict__ s1p,
        const float* __restrict__ s2p, const float* __restrict__ bias,
        float* __restrict__ out)
{
    __shared__ char  pool[32 * 1024];   // loop: w frags [2][16][512] u16 ; epilogue: apart[4][2048] f32
    __shared__ float dp0[512], dp1[512];

    u16*   wlp   = (u16*)pool;
    float* apart = (float*)pool;

    const int t  = threadIdx.x;
    const int wv = t >> 6, l = t & 63;
    const int lr = l & 15, lk = l >> 4;
    const int row0 = blockIdx.x * 32;
    const int nh = wv & 1, kq = wv >> 1;
    const int kl = wv * 32 + lk * 8;      // phase-A k offset within 256-tile

    const float s1r0 = s1p[row0 + lr];
    const float s1r1 = s1p[row0 + 16 + lr];
    const int* arow0 = adj + (size_t)(row0 + lr) * NN + kl;
    const int* arow1 = adj + (size_t)(row0 + 16 + lr) * NN + kl;

    // prefetch tile 0
    i32x4 pa0 = __builtin_nontemporal_load((const i32x4*)(arow0));
    i32x4 pa1 = __builtin_nontemporal_load((const i32x4*)(arow0 + 4));
    i32x4 pb0 = __builtin_nontemporal_load((const i32x4*)(arow1));
    i32x4 pb1 = __builtin_nontemporal_load((const i32x4*)(arow1 + 4));
    f32x4 s2a = *(const f32x4*)(s2p + kl);
    f32x4 s2b = *(const f32x4*)(s2p + kl + 4);

    f32x4 acc[2][2] = {};
    float d0 = 0.f, d1 = 0.f;

    for (int jt = 0; jt < 32; ++jt) {
        const int j0 = jt * 256;
        const int buf = jt & 1;

        // ---------------- phase A: w = mask ? exp2(lrelu') : 0 ----------------
        u16x8 w0, w1;
#pragma unroll
        for (int i = 0; i < 8; ++i) {
            const int   av = (i < 4) ? pa0[i] : pa1[i - 4];
            const float sv = (i < 4) ? s2a[i] : s2b[i - 4];
            float y = s1r0 + sv;
            float u = fmaxf(y, 0.2f * y);
            float w = EXP2F(u);
            w = (av != 0) ? w : 0.0f;
            const u16 wb = f2bf(w);
            w0[i] = wb;
            d0 += bf2f(wb);          // denom from the SAME bf16 weights
        }
#pragma unroll
        for (int i = 0; i < 8; ++i) {
            const int   av = (i < 4) ? pb0[i] : pb1[i - 4];
            const float sv = (i < 4) ? s2a[i] : s2b[i - 4];
            float y = s1r1 + sv;
            float u = fmaxf(y, 0.2f * y);
            float w = EXP2F(u);
            w = (av != 0) ? w : 0.0f;
            const u16 wb = f2bf(w);
            w1[i] = wb;
            d1 += bf2f(wb);
        }
        *(u16x8*)(wlp + ((buf * 16 + wv * 2 + 0) * 512 + l * 8)) = w0;
        *(u16x8*)(wlp + ((buf * 16 + wv * 2 + 1) * 512 + l * 8)) = w1;

        __syncthreads();

        // ------------- issue next-tile loads (in flight across B + next A) ----
        {
            const int jn = (jt + 1 < 32) ? (jt + 1) * 256 : 0;
            pa0 = __builtin_nontemporal_load((const i32x4*)(arow0 + jn));
            pa1 = __builtin_nontemporal_load((const i32x4*)(arow0 + jn + 4));
            pb0 = __builtin_nontemporal_load((const i32x4*)(arow1 + jn));
            pb1 = __builtin_nontemporal_load((const i32x4*)(arow1 + jn + 4));
            s2a = *(const f32x4*)(s2p + jn + kl);
            s2b = *(const f32x4*)(s2p + jn + kl + 4);
        }

        // ---------------- phase B: acc += w @ (z_hi + z_lo) -------------------
#pragma unroll
        for (int kk = 0; kk < 2; ++kk) {
            const int ks = kq * 2 + kk;
            const bf16x8 A0 = __builtin_bit_cast(bf16x8, *(const u16x8*)(wlp + ((buf * 16 + ks * 2 + 0) * 512 + l * 8)));
            const bf16x8 A1 = __builtin_bit_cast(bf16x8, *(const u16x8*)(wlp + ((buf * 16 + ks * 2 + 1) * 512 + l * 8)));
            const int jj = j0 + ks * 32 + lk * 8;
#pragma unroll
            for (int nt = 0; nt < 2; ++nt) {
                const int c = nh * 32 + nt * 16 + lr;
                const bf16x8 bh = __builtin_bit_cast(bf16x8, *(const u16x8*)(zt_hi + (size_t)c * NN + jj));
                const bf16x8 bl = __builtin_bit_cast(bf16x8, *(const u16x8*)(zt_lo + (size_t)c * NN + jj));
                acc[0][nt] = __builtin_amdgcn_mfma_f32_16x16x32_bf16(A0, bh, acc[0][nt], 0, 0, 0);
                acc[0][nt] = __builtin_amdgcn_mfma_f32_16x16x32_bf16(A0, bl, acc[0][nt], 0, 0, 0);
                acc[1][nt] = __builtin_amdgcn_mfma_f32_16x16x32_bf16(A1, bh, acc[1][nt], 0, 0, 0);
                acc[1][nt] = __builtin_amdgcn_mfma_f32_16x16x32_bf16(A1, bl, acc[1][nt], 0, 0, 0);
            }
        }
    }

    // ---------------- epilogue (deterministic reduction) ----------------------
    __syncthreads();              // all phase-B reads of wl done; reuse pool
    dp0[t] = d0;
    dp1[t] = d1;
#pragma unroll
    for (int mt = 0; mt < 2; ++mt)
#pragma unroll
        for (int nt = 0; nt < 2; ++nt)
#pragma unroll
            for (int r = 0; r < 4; ++r)
                apart[kq * 2048 + (mt * 16 + lk * 4 + r) * 64 + nh * 32 + nt * 16 + lr] = acc[mt][nt][r];
    __syncthreads();

    {
        const int r  = t >> 4;           // 0..31
        const int c0 = (t & 15) * 4;
        const int rr = r & 15;
        const float* dp = (r >> 4) ? dp1 : dp0;
        float den = 0.f;
#pragma unroll
        for (int w8 = 0; w8 < 8; ++w8)
#pragma unroll
            for (int k4 = 0; k4 < 4; ++k4)
                den += dp[w8 * 64 + k4 * 16 + rr];
        f32x4 val = {};
#pragma unroll
        for (int q = 0; q < 4; ++q)
            val += *(const f32x4*)(apart + q * 2048 + r * 64 + c0);
        const f32x4 bv = *(const f32x4*)(bias + c0);
        const float dinv = 1.0f / den;
        f32x4 o = val * dinv + bv;
        *(f32x4*)(out + (size_t)(row0 + r) * FOUT + c0) = o;
    }
}

// ---------------------------------------------------------------------------
extern "C" void kernel_launch(void* const* d_in, const int* in_sizes, int n_in,
                              void* d_out, int out_size, void* d_ws, size_t ws_size,
                              hipStream_t stream) {
    const float* input = (const float*)d_in[0];
    const int*   adj   = (const int*)d_in[1];
    const float* W     = (const float*)d_in[2];
    const float* a     = (const float*)d_in[3];
    const float* bias  = (const float*)d_in[4];
    float* out = (float*)d_out;

    char* ws = (char*)d_ws;
    u16*   wt_hi = (u16*)ws;   ws += FIN * FOUT * sizeof(u16);
    u16*   wt_lo = (u16*)ws;   ws += FIN * FOUT * sizeof(u16);
    float* z     = (float*)ws; ws += (size_t)NN * FOUT * sizeof(float);
    float* s1p   = (float*)ws; ws += NN * sizeof(float);
    float* s2p   = (float*)ws; ws += NN * sizeof(float);
    u16*   zt_hi = (u16*)ws;   ws += (size_t)NN * FOUT * sizeof(u16);
    u16*   zt_lo = (u16*)ws;   ws += (size_t)NN * FOUT * sizeof(u16);

    k_wt   <<<dim3(128), dim3(256), 0, stream>>>(W, wt_hi, wt_lo);
    k_zgemm<<<dim3(256), dim3(128), 0, stream>>>(input, wt_hi, wt_lo, a, z, s1p, s2p);
    k_zt   <<<dim3(256), dim3(128), 0, stream>>>(z, zt_hi, zt_lo);
    k_attn <<<dim3(256), dim3(512), 0, stream>>>(adj, zt_hi, zt_lo, s1p, s2p, bias, out);
}